// Round 2
// baseline (345.373 us; speedup 1.0000x reference)
//
#include <hip/hip_runtime.h>

#define N 4096
#define D 256
#define TS 64
#define KB 32
#define NB (N / TS)   // 64 tiles per dim

// ---------------- workspace layout (doubles) ----------------
// wsd[0..2]    : acc[3]       exp-sum accumulators (xx, yy, xy)
// wsd[8..519]  : cs[2][256]   column sums (x, y) in double
// wsd[520 ...] : float sq[2][4096]  row squared-norms
// then         : float coef[16]     3 pairs x 5 exp coefficients (log2e/bw_k)

// ---- K1: per-row squared norms (one wave per row) ----
__global__ void k_rowsq(const float* __restrict__ x, const float* __restrict__ y,
                        float* __restrict__ sq) {
    const int row = blockIdx.x;
    const int mat = blockIdx.y;
    const float* p = (mat ? y : x) + (size_t)row * D;
    const int t = threadIdx.x;  // 64 threads = 1 wave
    float4 v = ((const float4*)p)[t];
    float s = v.x * v.x + v.y * v.y + v.z * v.z + v.w * v.w;
    #pragma unroll
    for (int off = 32; off; off >>= 1) s += __shfl_down(s, off);
    if (t == 0) sq[mat * N + row] = s;
}

// ---- K2: column sums (double accumulate via atomics) ----
__global__ void k_colsum(const float* __restrict__ x, const float* __restrict__ y,
                         double* __restrict__ cs) {
    const int mat = blockIdx.y;
    const float* p = (mat ? y : x);
    const int t = threadIdx.x;           // 256 = column
    const int r0 = blockIdx.x * 32;      // 128 blocks x 32 rows
    float s = 0.f;
    #pragma unroll 8
    for (int r = 0; r < 32; ++r) s += p[(size_t)(r0 + r) * D + t];
    atomicAdd(&cs[mat * D + t], (double)s);
}

// ---- K3: reduce stats -> closed-form sum(d2) -> bandwidths -> coefs ----
__global__ void k_prep(const float* __restrict__ sq, const double* __restrict__ cs,
                       float* __restrict__ coef, double* __restrict__ acc) {
    const int t = threadIdx.x;  // 256
    double sx = 0, sy = 0;
    for (int i = t; i < N; i += 256) {
        sx += (double)sq[i];
        sy += (double)sq[N + i];
    }
    const double cx = cs[t], cy = cs[D + t];
    double v[5] = {sx, sy, cx * cx, cy * cy, cx * cy};
    #pragma unroll
    for (int k = 0; k < 5; ++k)
        for (int off = 32; off; off >>= 1) v[k] += __shfl_down(v[k], off);
    __shared__ double red[4][5];
    const int w = t >> 6, lane = t & 63;
    if (lane == 0)
        for (int k = 0; k < 5; ++k) red[w][k] = v[k];
    __syncthreads();
    if (t == 0) {
        double Sx = 0, Sy = 0, Cxx = 0, Cyy = 0, Cxy = 0;
        for (int q = 0; q < 4; ++q) {
            Sx += red[q][0]; Sy += red[q][1];
            Cxx += red[q][2]; Cyy += red[q][3]; Cxy += red[q][4];
        }
        const double ns = 2.0 * N;                 // n_samples = 8192
        const double denom = ns * ns - ns;
        const double sd[3] = {
            2.0 * N * Sx - 2.0 * Cxx,              // sum d2(x,x)
            2.0 * N * Sy - 2.0 * Cyy,              // sum d2(y,y)
            (double)N * Sx + (double)N * Sy - 2.0 * Cxy  // sum d2(x,y)
        };
        const double L2E = 1.4426950408889634;
        for (int p = 0; p < 3; ++p) {
            const double bw = sd[p] / denom / 4.0;  // / KERNEL_MUL^(5//2)
            for (int k = 0; k < 5; ++k) {
                const double bwk = bw * (double)(1 << k) + 1e-5;
                coef[p * 5 + k] = (float)(L2E / bwk);
            }
        }
        acc[0] = 0.0; acc[1] = 0.0; acc[2] = 0.0;
    }
}

// ---- K4: fused tile GEMM + 5-kernel exp reduction ----
__global__ __launch_bounds__(256) void k_mmd(
    const float* __restrict__ A, const float* __restrict__ B,
    const float* __restrict__ sqA, const float* __restrict__ sqB,
    const float* __restrict__ coef, double* __restrict__ acc, int tri) {
    // k-transposed LDS tiles; stride 68 keeps float4 rows 16B-aligned
    __shared__ float As[KB][TS + 4];
    __shared__ float Bs[KB][TS + 4];

    int bi, bj;
    if (tri) {  // decode upper-triangular tile index (bi <= bj)
        int rem = blockIdx.x, r = 0;
        while (rem >= NB - r) { rem -= NB - r; ++r; }
        bi = r; bj = r + rem;
    } else {
        bi = blockIdx.x >> 6; bj = blockIdx.x & 63;
    }

    const int tid = threadIdx.x;
    const int ty = tid >> 4, tx = tid & 15;
    const int lrow = tid >> 2;            // 0..63: which tile row this thread stages
    const int kc = (tid & 3) * 8;         // 8 contiguous k values

    const float* arow = A + (size_t)(bi * TS + lrow) * D + kc;
    const float* brow = B + (size_t)(bj * TS + lrow) * D + kc;

    float accr[4][4] = {};

    for (int k0 = 0; k0 < D; k0 += KB) {
        const float4 a0 = *(const float4*)(arow + k0);
        const float4 a1 = *(const float4*)(arow + k0 + 4);
        const float4 b0 = *(const float4*)(brow + k0);
        const float4 b1 = *(const float4*)(brow + k0 + 4);
        __syncthreads();  // previous compute done before overwrite
        As[kc + 0][lrow] = a0.x; As[kc + 1][lrow] = a0.y;
        As[kc + 2][lrow] = a0.z; As[kc + 3][lrow] = a0.w;
        As[kc + 4][lrow] = a1.x; As[kc + 5][lrow] = a1.y;
        As[kc + 6][lrow] = a1.z; As[kc + 7][lrow] = a1.w;
        Bs[kc + 0][lrow] = b0.x; Bs[kc + 1][lrow] = b0.y;
        Bs[kc + 2][lrow] = b0.z; Bs[kc + 3][lrow] = b0.w;
        Bs[kc + 4][lrow] = b1.x; Bs[kc + 5][lrow] = b1.y;
        Bs[kc + 6][lrow] = b1.z; Bs[kc + 7][lrow] = b1.w;
        __syncthreads();
        #pragma unroll
        for (int kk = 0; kk < KB; ++kk) {
            const float4 av = *(const float4*)&As[kk][ty * 4];
            const float4 bv = *(const float4*)&Bs[kk][tx * 4];
            const float a[4] = {av.x, av.y, av.z, av.w};
            const float b[4] = {bv.x, bv.y, bv.z, bv.w};
            #pragma unroll
            for (int i = 0; i < 4; ++i)
                #pragma unroll
                for (int j = 0; j < 4; ++j)
                    accr[i][j] = fmaf(a[i], b[j], accr[i][j]);
        }
    }

    // epilogue: d2 -> sum_k exp2(-d2 * coef_k)
    const float c0 = coef[0], c1 = coef[1], c2 = coef[2], c3 = coef[3], c4 = coef[4];
    const int row0 = bi * TS + ty * 4, col0 = bj * TS + tx * 4;
    float sqa[4], sqb[4];
    #pragma unroll
    for (int i = 0; i < 4; ++i) { sqa[i] = sqA[row0 + i]; sqb[i] = sqB[col0 + i]; }
    float s = 0.f;
    #pragma unroll
    for (int i = 0; i < 4; ++i)
        #pragma unroll
        for (int j = 0; j < 4; ++j) {
            const float d2 = fmaxf(sqa[i] + sqb[j] - 2.f * accr[i][j], 0.f);
            s += exp2f(-d2 * c0) + exp2f(-d2 * c1) + exp2f(-d2 * c2)
               + exp2f(-d2 * c3) + exp2f(-d2 * c4);
        }
    if (tri && bi != bj) s *= 2.f;

    double sd = (double)s;
    #pragma unroll
    for (int off = 32; off; off >>= 1) sd += __shfl_down(sd, off);
    __shared__ double red[4];
    if ((tid & 63) == 0) red[tid >> 6] = sd;
    __syncthreads();
    if (tid == 0) atomicAdd(acc, red[0] + red[1] + red[2] + red[3]);
}

// ---- K5: combine ----
__global__ void k_final(const double* __restrict__ acc, float* __restrict__ out) {
    const double inv = 1.0 / ((double)N * (double)N);
    out[0] = (float)((acc[0] + acc[1] - 2.0 * acc[2]) * inv);
}

extern "C" void kernel_launch(void* const* d_in, const int* in_sizes, int n_in,
                              void* d_out, int out_size, void* d_ws, size_t ws_size,
                              hipStream_t stream) {
    const float* x = (const float*)d_in[0];
    const float* y = (const float*)d_in[1];
    float* out = (float*)d_out;

    double* wsd = (double*)d_ws;
    double* acc = wsd;                       // 3 doubles
    double* cs  = wsd + 8;                   // 512 doubles
    float*  sq  = (float*)(wsd + 520);       // 8192 floats
    float*  coef = (float*)(wsd + 520) + 8192;  // 16 floats

    // zero acc + cs region (atomicAdd targets); ws is poisoned before each call
    hipMemsetAsync(d_ws, 0, 520 * sizeof(double), stream);

    k_rowsq<<<dim3(N, 2), 64, 0, stream>>>(x, y, sq);
    k_colsum<<<dim3(N / 32, 2), 256, 0, stream>>>(x, y, cs);
    k_prep<<<1, 256, 0, stream>>>(sq, cs, coef, acc);

    const int tri_blocks = NB * (NB + 1) / 2;  // 2080
    k_mmd<<<tri_blocks, 256, 0, stream>>>(x, x, sq, sq, coef + 0, &acc[0], 1);
    k_mmd<<<tri_blocks, 256, 0, stream>>>(y, y, sq + N, sq + N, coef + 1 * 5, &acc[1], 1);
    k_mmd<<<NB * NB, 256, 0, stream>>>(x, y, sq, sq + N, coef + 2 * 5, &acc[2], 0);

    k_final<<<1, 1, 0, stream>>>(acc, out);
}

// Round 3
// 198.822 us; speedup vs baseline: 1.7371x; 1.7371x over previous
//
#include <hip/hip_runtime.h>

#define N 4096
#define D 256
#define W 512          // converted row width in halves: [hi 256 | lo 256]
#define BT 128         // output tile
#define NB2 (N / BT)   // 32 tiles per dim
#define KT 24          // K-tiles of 32: effective K = 768 (h.h + h.l + l.h)

typedef __attribute__((ext_vector_type(8))) _Float16 f16x8;
typedef __attribute__((ext_vector_type(4))) _Float16 f16x4;
typedef __attribute__((ext_vector_type(4))) float f32x4;

__device__ __forceinline__ void gld_lds16(const void* g, void* l) {
    __builtin_amdgcn_global_load_lds(
        (const __attribute__((address_space(1))) unsigned int*)g,
        (__attribute__((address_space(3))) unsigned int*)l, 16, 0, 0);
}

// ---- K0: fp32 -> (hi, lo) f16 split, row-major [4096][512] ----
__global__ void k_cvt(const float* __restrict__ x, const float* __restrict__ y,
                      _Float16* __restrict__ xc, _Float16* __restrict__ yc) {
    const float* src = blockIdx.y ? y : x;
    _Float16* dst = blockIdx.y ? yc : xc;
    const int idx = (blockIdx.x * 256 + threadIdx.x) * 4;
    const int row = idx >> 8, k = idx & 255;
    const float4 v = *(const float4*)(src + idx);
    f16x4 h, l;
    h.x = (_Float16)v.x; h.y = (_Float16)v.y; h.z = (_Float16)v.z; h.w = (_Float16)v.w;
    l.x = (_Float16)(v.x - (float)h.x); l.y = (_Float16)(v.y - (float)h.y);
    l.z = (_Float16)(v.z - (float)h.z); l.w = (_Float16)(v.w - (float)h.w);
    *(f16x4*)(dst + (size_t)row * W + k) = h;
    *(f16x4*)(dst + (size_t)row * W + 256 + k) = l;
}

// ---- K1: per-row squared norms (fp32, one wave per row) ----
__global__ void k_rowsq(const float* __restrict__ x, const float* __restrict__ y,
                        float* __restrict__ sq) {
    const int row = blockIdx.x, mat = blockIdx.y;
    const float* p = (mat ? y : x) + (size_t)row * D;
    const int t = threadIdx.x;  // 64
    float4 v = ((const float4*)p)[t];
    float s = v.x * v.x + v.y * v.y + v.z * v.z + v.w * v.w;
    #pragma unroll
    for (int off = 32; off; off >>= 1) s += __shfl_down(s, off);
    if (t == 0) sq[mat * N + row] = s;
}

// ---- K2: column sums (closed-form bandwidth needs them) ----
__global__ void k_colsum(const float* __restrict__ x, const float* __restrict__ y,
                         double* __restrict__ cs) {
    const int mat = blockIdx.y;
    const float* p = (mat ? y : x);
    const int t = threadIdx.x;
    const int r0 = blockIdx.x * 32;
    float s = 0.f;
    #pragma unroll 8
    for (int r = 0; r < 32; ++r) s += p[(size_t)(r0 + r) * D + t];
    atomicAdd(&cs[mat * D + t], (double)s);
}

// ---- K3: stats -> sum(d2) closed form -> bandwidths -> exp2 coefficients ----
__global__ void k_prep(const float* __restrict__ sq, const double* __restrict__ cs,
                       float* __restrict__ coef, double* __restrict__ acc) {
    const int t = threadIdx.x;  // 256
    double sx = 0, sy = 0;
    for (int i = t; i < N; i += 256) { sx += (double)sq[i]; sy += (double)sq[N + i]; }
    const double cx = cs[t], cy = cs[D + t];
    double v[5] = {sx, sy, cx * cx, cy * cy, cx * cy};
    #pragma unroll
    for (int k = 0; k < 5; ++k)
        for (int off = 32; off; off >>= 1) v[k] += __shfl_down(v[k], off);
    __shared__ double red[4][5];
    const int w = t >> 6, lane = t & 63;
    if (lane == 0) for (int k = 0; k < 5; ++k) red[w][k] = v[k];
    __syncthreads();
    if (t == 0) {
        double Sx = 0, Sy = 0, Cxx = 0, Cyy = 0, Cxy = 0;
        for (int q = 0; q < 4; ++q) {
            Sx += red[q][0]; Sy += red[q][1];
            Cxx += red[q][2]; Cyy += red[q][3]; Cxy += red[q][4];
        }
        const double ns = 2.0 * N;
        const double denom = ns * ns - ns;
        const double sd[3] = {
            2.0 * N * Sx - 2.0 * Cxx,
            2.0 * N * Sy - 2.0 * Cyy,
            (double)N * Sx + (double)N * Sy - 2.0 * Cxy };
        const double L2E = 1.4426950408889634;
        for (int p = 0; p < 3; ++p) {
            const double bw = sd[p] / denom / 4.0;
            for (int k = 0; k < 5; ++k)
                coef[p * 5 + k] = (float)(L2E / (bw * (double)(1 << k) + 1e-5));
        }
        acc[0] = 0.0; acc[1] = 0.0; acc[2] = 0.0;
    }
}

// ---- K4: MFMA f16-split Gram tile + fused 5-bandwidth exp2 reduction ----
// LDS: [128 rows][32 halves], 16B chunks XOR-swizzled (c ^= (row>>1)&3) via
// pre-swizzled global source addresses (global_load_lds writes linearly).
__global__ __launch_bounds__(256) void k_mmd(
    const _Float16* __restrict__ A, const _Float16* __restrict__ B,
    const float* __restrict__ sqA, const float* __restrict__ sqB,
    const float* __restrict__ coef, double* __restrict__ acc, int tri) {
    __shared__ __align__(16) _Float16 As[BT * 32];
    __shared__ __align__(16) _Float16 Bs[BT * 32];
    __shared__ double red[4];

    // XCD-aware swizzle (gridDim.x % 8 == 0 for 528 and 1024)
    const int nwg = gridDim.x;
    int bid = (blockIdx.x & 7) * (nwg >> 3) + (blockIdx.x >> 3);

    int bi, bj;
    if (tri) {
        int rem = bid, r = 0;
        while (rem >= NB2 - r) { rem -= NB2 - r; ++r; }
        bi = r; bj = r + rem;
    } else { bi = bid >> 5; bj = bid & 31; }

    const int tid = threadIdx.x;
    // --- staging addresses: thread t fills LDS linear slot t*16 (+q*4096) ---
    const int sr = tid >> 2;                         // staging row (q adds 64)
    const int swc = (tid & 3) ^ ((sr >> 1) & 3);     // swizzled source chunk
    const char* gA = (const char*)(A + (size_t)(bi * BT + sr) * W) + swc * 16;
    const char* gB = (const char*)(B + (size_t)(bj * BT + sr) * W) + swc * 16;
    char* lA = (char*)As + tid * 16;
    char* lB = (char*)Bs + tid * 16;

    // --- fragment addresses ---
    const int lane = tid & 63, w = tid >> 6;
    const int wr = (w >> 1) * 64, wc = (w & 1) * 64;   // wave quadrant
    const int fr = lane & 15;                          // fragment row/col
    const int pg = (((lane >> 4) ^ ((fr >> 1) & 3)) * 16);  // swizzled k-chunk byte off
    const char* rA = (const char*)As + pg;
    const char* rB = (const char*)Bs + pg;

    f32x4 accv[4][4];
    #pragma unroll
    for (int m = 0; m < 4; ++m)
        #pragma unroll
        for (int n = 0; n < 4; ++n) accv[m][n] = {0.f, 0.f, 0.f, 0.f};

    for (int kt = 0; kt < KT; ++kt) {
        const int sec = kt >> 3;                 // 0: h.h  1: h.l  2: l.h
        const int kofA = (((kt & 7) * 32) + (sec == 2 ? 256 : 0)) * 2;
        const int kofB = (((kt & 7) * 32) + (sec == 1 ? 256 : 0)) * 2;
        __syncthreads();                          // previous tile's reads done
        gld_lds16(gA + kofA, lA);
        gld_lds16(gA + kofA + 64 * 1024, lA + 4096);
        gld_lds16(gB + kofB, lB);
        gld_lds16(gB + kofB + 64 * 1024, lB + 4096);
        __syncthreads();                          // loads landed (vmcnt drained)
        f16x8 af[4], bf[4];
        #pragma unroll
        for (int m = 0; m < 4; ++m)
            af[m] = *(const f16x8*)(rA + (wr + m * 16 + fr) * 64);
        #pragma unroll
        for (int n = 0; n < 4; ++n)
            bf[n] = *(const f16x8*)(rB + (wc + n * 16 + fr) * 64);
        #pragma unroll
        for (int m = 0; m < 4; ++m)
            #pragma unroll
            for (int n = 0; n < 4; ++n)
                accv[m][n] = __builtin_amdgcn_mfma_f32_16x16x32_f16(
                    af[m], bf[n], accv[m][n], 0, 0, 0);
    }

    // --- epilogue: d2 = sqa + sqb - 2*dot -> sum_k exp2(-d2*coef_k) ---
    const float c0 = coef[0], c1 = coef[1], c2 = coef[2], c3 = coef[3], c4 = coef[4];
    const int row0 = bi * BT + wr + (lane >> 4) * 4;   // C/D: row=(l>>4)*4+reg
    const int col0 = bj * BT + wc + fr;                // C/D: col=l&15
    float s = 0.f;
    #pragma unroll
    for (int m = 0; m < 4; ++m) {
        const f32x4 sa = *(const f32x4*)(sqA + row0 + m * 16);
        #pragma unroll
        for (int n = 0; n < 4; ++n) {
            const float sb = sqB[col0 + n * 16];
            #pragma unroll
            for (int i = 0; i < 4; ++i) {
                const float d2 = fmaxf(sa[i] + sb - 2.f * accv[m][n][i], 0.f);
                s += exp2f(-d2 * c0) + exp2f(-d2 * c1) + exp2f(-d2 * c2)
                   + exp2f(-d2 * c3) + exp2f(-d2 * c4);
            }
        }
    }
    if (tri && bi != bj) s *= 2.f;

    double sd = (double)s;
    #pragma unroll
    for (int off = 32; off; off >>= 1) sd += __shfl_down(sd, off);
    if (lane == 0) red[w] = sd;
    __syncthreads();
    if (tid == 0) atomicAdd(acc, red[0] + red[1] + red[2] + red[3]);
}

// ---- K5: combine ----
__global__ void k_final(const double* __restrict__ acc, float* __restrict__ out) {
    const double inv = 1.0 / ((double)N * (double)N);
    out[0] = (float)((acc[0] + acc[1] - 2.0 * acc[2]) * inv);
}

extern "C" void kernel_launch(void* const* d_in, const int* in_sizes, int n_in,
                              void* d_out, int out_size, void* d_ws, size_t ws_size,
                              hipStream_t stream) {
    const float* x = (const float*)d_in[0];
    const float* y = (const float*)d_in[1];
    float* out = (float*)d_out;

    double* wsd = (double*)d_ws;
    double* acc = wsd;                        // 3 doubles
    double* cs  = wsd + 8;                    // 512 doubles
    float*  sq  = (float*)(wsd + 520);        // 8192 floats
    float*  coef = sq + 2 * N;                // 16 floats
    char* base = (char*)d_ws;
    _Float16* xc = (_Float16*)(base + 40960);                       // 4 MB
    _Float16* yc = (_Float16*)(base + 40960 + (size_t)N * W * 2);   // 4 MB

    hipMemsetAsync(d_ws, 0, 520 * sizeof(double), stream);

    k_cvt<<<dim3(N * D / 4 / 256, 2), 256, 0, stream>>>(x, y, xc, yc);
    k_rowsq<<<dim3(N, 2), 64, 0, stream>>>(x, y, sq);
    k_colsum<<<dim3(N / 32, 2), 256, 0, stream>>>(x, y, cs);
    k_prep<<<1, 256, 0, stream>>>(sq, cs, coef, acc);

    const int tri_blocks = NB2 * (NB2 + 1) / 2;  // 528
    k_mmd<<<tri_blocks, 256, 0, stream>>>(xc, xc, sq, sq, coef + 0, &acc[0], 1);
    k_mmd<<<tri_blocks, 256, 0, stream>>>(yc, yc, sq + N, sq + N, coef + 5, &acc[1], 1);
    k_mmd<<<NB2 * NB2, 256, 0, stream>>>(xc, yc, sq, sq + N, coef + 10, &acc[2], 0);

    k_final<<<1, 1, 0, stream>>>(acc, out);
}

// Round 4
// 137.033 us; speedup vs baseline: 2.5204x; 1.4509x over previous
//
#include <hip/hip_runtime.h>

#define N 4096
#define D 256
#define BT 128
#define NB2 32             // N/BT tiles per dim
#define TRI 528            // NB2*(NB2+1)/2
#define TOTAL 2080         // TRI + TRI + NB2*NB2
#define BK 64              // K-step (halves)
#define KT (D / BK)        // 4 K-steps

typedef __attribute__((ext_vector_type(8))) _Float16 f16x8;
typedef __attribute__((ext_vector_type(4))) _Float16 f16x4;
typedef __attribute__((ext_vector_type(4))) float f32x4;

__device__ __forceinline__ void gld_lds16(const void* g, void* l) {
    __builtin_amdgcn_global_load_lds(
        (const __attribute__((address_space(1))) unsigned int*)g,
        (__attribute__((address_space(3))) unsigned int*)l, 16, 0, 0);
}

// ---- K0: fp32 -> fp16 convert + per-row squared norms (fp32), fused ----
__global__ void k_cvt(const float* __restrict__ x, const float* __restrict__ y,
                      _Float16* __restrict__ xc, _Float16* __restrict__ yc,
                      float* __restrict__ sq) {
    const int mat = blockIdx.y;
    const float* src = mat ? y : x;
    _Float16* dst = mat ? yc : xc;
    const int row = blockIdx.x * 4 + (threadIdx.x >> 6);  // 4 rows/block, 1 wave each
    const int lane = threadIdx.x & 63;
    const float4 v = *(const float4*)(src + (size_t)row * D + lane * 4);
    f16x4 h;
    h.x = (_Float16)v.x; h.y = (_Float16)v.y; h.z = (_Float16)v.z; h.w = (_Float16)v.w;
    *(f16x4*)(dst + (size_t)row * D + lane * 4) = h;
    float s = v.x * v.x + v.y * v.y + v.z * v.z + v.w * v.w;
    #pragma unroll
    for (int off = 32; off; off >>= 1) s += __shfl_down(s, off);
    if (lane == 0) sq[mat * N + row] = s;
}

// ---- K2: column sums in double (for closed-form sum(d2)) ----
__global__ void k_colsum(const float* __restrict__ x, const float* __restrict__ y,
                         double* __restrict__ cs) {
    const int mat = blockIdx.y;
    const float* p = (mat ? y : x);
    const int t = threadIdx.x;
    const int r0 = blockIdx.x * 32;
    float s = 0.f;
    #pragma unroll 8
    for (int r = 0; r < 32; ++r) s += p[(size_t)(r0 + r) * D + t];
    atomicAdd(&cs[mat * D + t], (double)s);
}

// ---- K3: stats -> closed-form sum(d2) -> bandwidths -> exp2 coefficients ----
__global__ void k_prep(const float* __restrict__ sq, const double* __restrict__ cs,
                       float* __restrict__ coef, double* __restrict__ acc) {
    const int t = threadIdx.x;  // 256
    double sx = 0, sy = 0;
    for (int i = t; i < N; i += 256) { sx += (double)sq[i]; sy += (double)sq[N + i]; }
    const double cx = cs[t], cy = cs[D + t];
    double v[5] = {sx, sy, cx * cx, cy * cy, cx * cy};
    #pragma unroll
    for (int k = 0; k < 5; ++k)
        for (int off = 32; off; off >>= 1) v[k] += __shfl_down(v[k], off);
    __shared__ double red[4][5];
    const int w = t >> 6, lane = t & 63;
    if (lane == 0) for (int k = 0; k < 5; ++k) red[w][k] = v[k];
    __syncthreads();
    if (t == 0) {
        double Sx = 0, Sy = 0, Cxx = 0, Cyy = 0, Cxy = 0;
        for (int q = 0; q < 4; ++q) {
            Sx += red[q][0]; Sy += red[q][1];
            Cxx += red[q][2]; Cyy += red[q][3]; Cxy += red[q][4];
        }
        const double ns = 2.0 * N;
        const double denom = ns * ns - ns;
        const double sd[3] = {
            2.0 * N * Sx - 2.0 * Cxx,
            2.0 * N * Sy - 2.0 * Cyy,
            (double)N * Sx + (double)N * Sy - 2.0 * Cxy };
        const double L2E = 1.4426950408889634;
        for (int p = 0; p < 3; ++p) {
            const double bw = sd[p] / denom / 4.0;
            for (int k = 0; k < 5; ++k)
                coef[p * 5 + k] = (float)(L2E / (bw * (double)(1 << k) + 1e-5));
        }
        acc[0] = 0.0; acc[1] = 0.0; acc[2] = 0.0;
    }
}

// ---- K4: ALL THREE passes in one dispatch. Pure-fp16 MFMA Gram (K=256),
// BK=64 single-buffered LDS, chunk-XOR swizzle via pre-swizzled global src,
// fused 5-bandwidth exp2 reduction. ----
__global__ __launch_bounds__(256) void k_mmd(
    const _Float16* __restrict__ xc, const _Float16* __restrict__ yc,
    const float* __restrict__ sq, const float* __restrict__ coefs,
    double* __restrict__ acc) {
    __shared__ __align__(16) _Float16 As[BT * BK];   // 16 KB, [128 rows][64 halves]
    __shared__ __align__(16) _Float16 Bs[BT * BK];   // 16 KB
    __shared__ double red[4];

    // XCD-aware swizzle (TOTAL % 8 == 0)
    const int bid = (blockIdx.x & 7) * (TOTAL / 8) + (blockIdx.x >> 3);

    // pass decode: 0 = xx (tri), 1 = yy (tri), 2 = xy (full)
    int p, b;
    if (bid < TRI)          { p = 0; b = bid; }
    else if (bid < 2 * TRI) { p = 1; b = bid - TRI; }
    else                    { p = 2; b = bid - 2 * TRI; }
    const _Float16* A = (p == 1) ? yc : xc;
    const _Float16* B = (p == 0) ? xc : yc;
    const float* sqA = (p == 1) ? sq + N : sq;
    const float* sqB = (p == 0) ? sq : sq + N;
    const float* coef = coefs + p * 5;

    int bi, bj;
    if (p < 2) {  // upper-triangular decode (bi <= bj)
        int rem = b, r = 0;
        while (rem >= NB2 - r) { rem -= NB2 - r; ++r; }
        bi = r; bj = r + rem;
    } else { bi = b >> 5; bj = b & 31; }

    const int tid = threadIdx.x;
    // --- staging: thread t fills LDS linear slot t*16 (+q*4096, q=0..3) ---
    // LDS row = q*32 + (t>>3), chunk = t&7; source chunk XOR-swizzled by row&7
    // (row&7 == (t>>3)&7 for all q since q*32 is a multiple of 8).
    const int srow = tid >> 3;
    const int sc = (tid & 7) ^ (srow & 7);
    const char* gA = (const char*)A + ((size_t)(bi * BT + srow) * D) * 2 + sc * 16;
    const char* gB = (const char*)B + ((size_t)(bj * BT + srow) * D) * 2 + sc * 16;
    char* lA = (char*)As + tid * 16;
    char* lB = (char*)Bs + tid * 16;

    // --- fragment read addressing ---
    const int lane = tid & 63, w = tid >> 6;
    const int wr = (w >> 1) * 64, wc = (w & 1) * 64;   // wave quadrant
    const int fr = lane & 15;
    const int lg = lane >> 4;                          // k-group within MFMA
    // chunk byte offsets for the two K=32 halves of a BK=64 step (XOR-swizzled)
    const int ch0 = ((lg)     ^ (fr & 7)) * 16;
    const int ch1 = ((lg + 4) ^ (fr & 7)) * 16;
    const char* rA = (const char*)As + (wr + fr) * 128;
    const char* rB = (const char*)Bs + (wc + fr) * 128;

    f32x4 accv[4][4];
    #pragma unroll
    for (int m = 0; m < 4; ++m)
        #pragma unroll
        for (int n = 0; n < 4; ++n) accv[m][n] = {0.f, 0.f, 0.f, 0.f};

    for (int kt = 0; kt < KT; ++kt) {
        const int kb = kt * (BK * 2);  // byte offset along K
        __syncthreads();               // previous tile's LDS reads done
        #pragma unroll
        for (int q = 0; q < 4; ++q) {
            gld_lds16(gA + kb + q * 16384, lA + q * 4096);
            gld_lds16(gB + kb + q * 16384, lB + q * 4096);
        }
        __syncthreads();               // loads landed
        #pragma unroll
        for (int kg = 0; kg < 2; ++kg) {
            const int ch = kg ? ch1 : ch0;
            f16x8 af[4], bf[4];
            #pragma unroll
            for (int m = 0; m < 4; ++m)
                af[m] = *(const f16x8*)(rA + m * 2048 + ch);
            #pragma unroll
            for (int n = 0; n < 4; ++n)
                bf[n] = *(const f16x8*)(rB + n * 2048 + ch);
            #pragma unroll
            for (int m = 0; m < 4; ++m)
                #pragma unroll
                for (int n = 0; n < 4; ++n)
                    accv[m][n] = __builtin_amdgcn_mfma_f32_16x16x32_f16(
                        af[m], bf[n], accv[m][n], 0, 0, 0);
        }
    }

    // --- epilogue: d2 = sqa + sqb - 2*dot -> sum_k exp2(-d2*coef_k) ---
    const float c0 = coef[0], c1 = coef[1], c2 = coef[2], c3 = coef[3], c4 = coef[4];
    const int row0 = bi * BT + wr + (lane >> 4) * 4;   // C/D: row=(l>>4)*4+reg
    const int col0 = bj * BT + wc + fr;                // C/D: col=l&15
    float s = 0.f;
    #pragma unroll
    for (int m = 0; m < 4; ++m) {
        const f32x4 sa = *(const f32x4*)(sqA + row0 + m * 16);
        #pragma unroll
        for (int n = 0; n < 4; ++n) {
            const float sb = sqB[col0 + n * 16];
            #pragma unroll
            for (int i = 0; i < 4; ++i) {
                const float d2 = fmaxf(sa[i] + sb - 2.f * accv[m][n][i], 0.f);
                s += exp2f(-d2 * c0) + exp2f(-d2 * c1) + exp2f(-d2 * c2)
                   + exp2f(-d2 * c3) + exp2f(-d2 * c4);
            }
        }
    }
    if (p < 2 && bi != bj) s *= 2.f;   // triangular symmetry weight

    double sd = (double)s;
    #pragma unroll
    for (int off = 32; off; off >>= 1) sd += __shfl_down(sd, off);
    if (lane == 0) red[w] = sd;
    __syncthreads();
    if (tid == 0) atomicAdd(&acc[p], red[0] + red[1] + red[2] + red[3]);
}

// ---- K5: combine ----
__global__ void k_final(const double* __restrict__ acc, float* __restrict__ out) {
    const double inv = 1.0 / ((double)N * (double)N);
    out[0] = (float)((acc[0] + acc[1] - 2.0 * acc[2]) * inv);
}

extern "C" void kernel_launch(void* const* d_in, const int* in_sizes, int n_in,
                              void* d_out, int out_size, void* d_ws, size_t ws_size,
                              hipStream_t stream) {
    const float* x = (const float*)d_in[0];
    const float* y = (const float*)d_in[1];
    float* out = (float*)d_out;

    double* wsd = (double*)d_ws;
    double* acc = wsd;                        // 3 doubles
    double* cs  = wsd + 8;                    // 512 doubles
    float*  sq  = (float*)(wsd + 520);        // 8192 floats
    float*  coef = sq + 2 * N;                // 16 floats
    char* base = (char*)d_ws;
    _Float16* xc = (_Float16*)(base + 40960);                       // 2 MB
    _Float16* yc = (_Float16*)(base + 40960 + (size_t)N * D * 2);   // 2 MB

    hipMemsetAsync(d_ws, 0, 520 * sizeof(double), stream);

    k_cvt<<<dim3(N / 4, 2), 256, 0, stream>>>(x, y, xc, yc, sq);
    k_colsum<<<dim3(N / 32, 2), 256, 0, stream>>>(x, y, cs);
    k_prep<<<1, 256, 0, stream>>>(sq, cs, coef, acc);
    k_mmd<<<TOTAL, 256, 0, stream>>>(xc, yc, sq, coef, acc);
    k_final<<<1, 1, 0, stream>>>(acc, out);
}

// Round 5
// 116.898 us; speedup vs baseline: 2.9545x; 1.1722x over previous
//
#include <hip/hip_runtime.h>

#define N 4096
#define D 256
#define BT 128
#define NB2 32             // N/BT tiles per dim
#define TRI 528            // NB2*(NB2+1)/2
#define TOTAL 2080         // TRI + TRI + NB2*NB2
#define BK 32              // K-step (halves)
#define KT (D / BK)        // 8 K-steps

typedef __attribute__((ext_vector_type(8))) _Float16 f16x8;
typedef __attribute__((ext_vector_type(4))) _Float16 f16x4;
typedef __attribute__((ext_vector_type(4))) float f32x4;

__device__ __forceinline__ void gld_lds16(const void* g, void* l) {
    __builtin_amdgcn_global_load_lds(
        (const __attribute__((address_space(1))) unsigned int*)g,
        (__attribute__((address_space(3))) unsigned int*)l, 16, 0, 0);
}

// ---- K0: fp32 -> fp16 convert + per-row squared norms + cs zeroing ----
__global__ void k_cvt(const float* __restrict__ x, const float* __restrict__ y,
                      _Float16* __restrict__ xc, _Float16* __restrict__ yc,
                      float* __restrict__ sq, double* __restrict__ cs) {
    const int mat = blockIdx.y;
    if (blockIdx.x == 0) cs[mat * D + threadIdx.x] = 0.0;  // zero atomic targets
    const float* src = mat ? y : x;
    _Float16* dst = mat ? yc : xc;
    const int row = blockIdx.x * 4 + (threadIdx.x >> 6);  // 4 rows/block
    const int lane = threadIdx.x & 63;
    const float4 v = *(const float4*)(src + (size_t)row * D + lane * 4);
    f16x4 h;
    h.x = (_Float16)v.x; h.y = (_Float16)v.y; h.z = (_Float16)v.z; h.w = (_Float16)v.w;
    *(f16x4*)(dst + (size_t)row * D + lane * 4) = h;
    float s = v.x * v.x + v.y * v.y + v.z * v.z + v.w * v.w;
    #pragma unroll
    for (int off = 32; off; off >>= 1) s += __shfl_down(s, off);
    if (lane == 0) sq[mat * N + row] = s;
}

// ---- K2: column sums in double (for closed-form sum(d2)) ----
__global__ void k_colsum(const float* __restrict__ x, const float* __restrict__ y,
                         double* __restrict__ cs) {
    const int mat = blockIdx.y;
    const float* p = (mat ? y : x);
    const int t = threadIdx.x;
    const int r0 = blockIdx.x * 32;
    float s = 0.f;
    #pragma unroll 8
    for (int r = 0; r < 32; ++r) s += p[(size_t)(r0 + r) * D + t];
    atomicAdd(&cs[mat * D + t], (double)s);
}

// ---- K3: stats -> closed-form sum(d2) -> base coefficient c4 per pass ----
// Terms are u^(2^(4-k)) with u = exp2(-d2*c4), c4 = L2E/(16*bw + eps).
__global__ void k_prep(const float* __restrict__ sq, const double* __restrict__ cs,
                       float* __restrict__ coef, double* __restrict__ acc) {
    const int t = threadIdx.x;  // 256
    double sx = 0, sy = 0;
    for (int i = t; i < N; i += 256) { sx += (double)sq[i]; sy += (double)sq[N + i]; }
    const double cx = cs[t], cy = cs[D + t];
    double v[5] = {sx, sy, cx * cx, cy * cy, cx * cy};
    #pragma unroll
    for (int k = 0; k < 5; ++k)
        for (int off = 32; off; off >>= 1) v[k] += __shfl_down(v[k], off);
    __shared__ double red[4][5];
    const int w = t >> 6, lane = t & 63;
    if (lane == 0) for (int k = 0; k < 5; ++k) red[w][k] = v[k];
    __syncthreads();
    if (t == 0) {
        double Sx = 0, Sy = 0, Cxx = 0, Cyy = 0, Cxy = 0;
        for (int q = 0; q < 4; ++q) {
            Sx += red[q][0]; Sy += red[q][1];
            Cxx += red[q][2]; Cyy += red[q][3]; Cxy += red[q][4];
        }
        const double ns = 2.0 * N;
        const double denom = ns * ns - ns;
        const double sd[3] = {
            2.0 * N * Sx - 2.0 * Cxx,
            2.0 * N * Sy - 2.0 * Cyy,
            (double)N * Sx + (double)N * Sy - 2.0 * Cxy };
        const double L2E = 1.4426950408889634;
        for (int p = 0; p < 3; ++p) {
            const double bw = sd[p] / denom / 4.0;
            coef[p] = (float)(L2E / (16.0 * bw + 1e-5));
        }
        acc[0] = 0.0; acc[1] = 0.0; acc[2] = 0.0;
    }
}

// ---- K4: all three passes in one dispatch. fp16 MFMA Gram (K=256), BK=32
// single-buffered LDS (16.4 KB -> ~6 blocks/CU), chunk-XOR swizzle via
// pre-swizzled global source, factored single-exp 5-bandwidth epilogue. ----
__global__ __launch_bounds__(256) void k_mmd(
    const _Float16* __restrict__ xc, const _Float16* __restrict__ yc,
    const float* __restrict__ sq, const float* __restrict__ coefs,
    double* __restrict__ acc) {
    __shared__ __align__(16) _Float16 As[BT * BK];   // 8 KB, [128 rows][32 halves]
    __shared__ __align__(16) _Float16 Bs[BT * BK];   // 8 KB
    __shared__ double red[4];

    // XCD-aware swizzle (TOTAL % 8 == 0)
    const int bid = (blockIdx.x & 7) * (TOTAL / 8) + (blockIdx.x >> 3);

    // pass decode: 0 = xx (tri), 1 = yy (tri), 2 = xy (full)
    int p, b;
    if (bid < TRI)          { p = 0; b = bid; }
    else if (bid < 2 * TRI) { p = 1; b = bid - TRI; }
    else                    { p = 2; b = bid - 2 * TRI; }
    const _Float16* A = (p == 1) ? yc : xc;
    const _Float16* B = (p == 0) ? xc : yc;
    const float* sqA = (p == 1) ? sq + N : sq;
    const float* sqB = (p == 0) ? sq : sq + N;
    const float c4 = coefs[p];

    int bi, bj;
    if (p < 2) {  // upper-triangular decode (bi <= bj)
        int rem = b, r = 0;
        while (rem >= NB2 - r) { rem -= NB2 - r; ++r; }
        bi = r; bj = r + rem;
    } else { bi = b >> 5; bj = b & 31; }

    const int tid = threadIdx.x;
    // --- staging: thread t fills LDS slot t*16 (+q*4096, q=0..1) ---
    // LDS row = q*64 + (t>>2), pos = t&3; source chunk = pos ^ (row&3);
    // (row&3) == ((t>>2)&3) for both q since q*64 % 4 == 0.
    const int srow = tid >> 2;
    const int sc = (tid & 3) ^ (srow & 3);
    const char* gA = (const char*)A + (size_t)(bi * BT + srow) * (D * 2) + sc * 16;
    const char* gB = (const char*)B + (size_t)(bj * BT + srow) * (D * 2) + sc * 16;
    char* lA = (char*)As + tid * 16;
    char* lB = (char*)Bs + tid * 16;

    // --- fragment read addressing ---
    const int lane = tid & 63, w = tid >> 6;
    const int wr = (w >> 1) * 64, wc = (w & 1) * 64;   // wave quadrant
    const int fr = lane & 15;
    const int lg = lane >> 4;                          // k-chunk within MFMA
    const int ch = (lg ^ (fr & 3)) * 16;               // XOR-swizzled chunk byte off
    const char* rA = (const char*)As + (wr + fr) * 64 + ch;
    const char* rB = (const char*)Bs + (wc + fr) * 64 + ch;

    f32x4 accv[4][4];
    #pragma unroll
    for (int m = 0; m < 4; ++m)
        #pragma unroll
        for (int n = 0; n < 4; ++n) accv[m][n] = {0.f, 0.f, 0.f, 0.f};

    for (int kt = 0; kt < KT; ++kt) {
        const int kb = kt * (BK * 2);      // byte offset along K
        __syncthreads();                    // previous step's LDS reads done
        gld_lds16(gA + kb, lA);
        gld_lds16(gA + kb + 64 * (D * 2), lA + 4096);   // rows 64..127
        gld_lds16(gB + kb, lB);
        gld_lds16(gB + kb + 64 * (D * 2), lB + 4096);
        __syncthreads();                    // loads landed
        f16x8 af[4], bf[4];
        #pragma unroll
        for (int m = 0; m < 4; ++m)
            af[m] = *(const f16x8*)(rA + m * 1024);
        #pragma unroll
        for (int n = 0; n < 4; ++n)
            bf[n] = *(const f16x8*)(rB + n * 1024);
        #pragma unroll
        for (int m = 0; m < 4; ++m)
            #pragma unroll
            for (int n = 0; n < 4; ++n)
                accv[m][n] = __builtin_amdgcn_mfma_f32_16x16x32_f16(
                    af[m], bf[n], accv[m][n], 0, 0, 0);
    }

    // --- epilogue: arg = -d2*c4 (clamped <= 0); u = exp2(arg);
    //     sum over 5 bandwidths = u + u^2 + u^4 + u^8 + u^16 ---
    const float c2x = 2.f * c4;
    const int row0 = bi * BT + wr + (lane >> 4) * 4;   // C/D: row=(l>>4)*4+reg
    const int col0 = bj * BT + wc + fr;                // C/D: col=l&15
    float asa[4][4], bsb[4];
    #pragma unroll
    for (int m = 0; m < 4; ++m) {
        const f32x4 sa = *(const f32x4*)(sqA + row0 + m * 16);
        #pragma unroll
        for (int i = 0; i < 4; ++i) asa[m][i] = sa[i] * c4;
    }
    #pragma unroll
    for (int n = 0; n < 4; ++n) bsb[n] = sqB[col0 + n * 16] * c4;
    float s = 0.f;
    #pragma unroll
    for (int m = 0; m < 4; ++m)
        #pragma unroll
        for (int n = 0; n < 4; ++n)
            #pragma unroll
            for (int i = 0; i < 4; ++i) {
                float arg = fmaf(accv[m][n][i], c2x, -(asa[m][i] + bsb[n]));
                arg = fminf(arg, 0.f);                 // d2 >= 0 clamp
                const float u = __builtin_amdgcn_exp2f(arg);
                const float u2 = u * u, u4 = u2 * u2;
                const float u8 = u4 * u4, u16 = u8 * u8;
                s += (u + u2) + (u4 + u8) + u16;
            }
    if (p < 2 && bi != bj) s *= 2.f;   // triangular symmetry weight

    double sd = (double)s;
    #pragma unroll
    for (int off = 32; off; off >>= 1) sd += __shfl_down(sd, off);
    if (lane == 0) red[w] = sd;
    __syncthreads();
    if (tid == 0) atomicAdd(&acc[p], red[0] + red[1] + red[2] + red[3]);
}

// ---- K5: combine ----
__global__ void k_final(const double* __restrict__ acc, float* __restrict__ out) {
    const double inv = 1.0 / ((double)N * (double)N);
    out[0] = (float)((acc[0] + acc[1] - 2.0 * acc[2]) * inv);
}

extern "C" void kernel_launch(void* const* d_in, const int* in_sizes, int n_in,
                              void* d_out, int out_size, void* d_ws, size_t ws_size,
                              hipStream_t stream) {
    const float* x = (const float*)d_in[0];
    const float* y = (const float*)d_in[1];
    float* out = (float*)d_out;

    double* wsd = (double*)d_ws;
    double* acc = wsd;                        // 3 doubles
    double* cs  = wsd + 8;                    // 512 doubles
    float*  sq  = (float*)(wsd + 520);        // 8192 floats
    float*  coef = sq + 2 * N;                // 3 floats
    char* base = (char*)d_ws;
    _Float16* xc = (_Float16*)(base + 40960);                       // 2 MB
    _Float16* yc = (_Float16*)(base + 40960 + (size_t)N * D * 2);   // 2 MB

    k_cvt<<<dim3(N / 4, 2), 256, 0, stream>>>(x, y, xc, yc, sq, cs);
    k_colsum<<<dim3(N / 32, 2), 256, 0, stream>>>(x, y, cs);
    k_prep<<<1, 256, 0, stream>>>(sq, cs, coef, acc);
    k_mmd<<<TOTAL, 256, 0, stream>>>(xc, yc, sq, coef, acc);
    k_final<<<1, 1, 0, stream>>>(acc, out);
}

// Round 7
// 116.170 us; speedup vs baseline: 2.9730x; 1.0063x over previous
//
#include <hip/hip_runtime.h>

#define N 4096
#define D 256
#define BT 128
#define NB2 32             // N/BT tiles per dim
#define TRI 528            // NB2*(NB2+1)/2
#define TOTAL 2080         // TRI + TRI + NB2*NB2
#define BK 32              // K-step (halves)
#define KT (D / BK)        // 8 K-steps

typedef __attribute__((ext_vector_type(8))) _Float16 f16x8;
typedef __attribute__((ext_vector_type(4))) _Float16 f16x4;
typedef __attribute__((ext_vector_type(4))) float f32x4;

__device__ __forceinline__ void gld_lds16(const void* g, void* l) {
    __builtin_amdgcn_global_load_lds(
        (const __attribute__((address_space(1))) unsigned int*)g,
        (__attribute__((address_space(3))) unsigned int*)l, 16, 0, 0);
}

// ---- K1: fp32 -> fp16 convert + row squared norms + column-sum partials ----
// 32 rows/block (wave w owns rows r0+8w..+8). Column sums via per-block LDS
// reduce -> 256 atomicAdds/block (atomic-WRITE-only fusion: replay-safe).
// cs is zeroed by a hipMemsetAsync node before this kernel.
__global__ void k_cvt(const float* __restrict__ x, const float* __restrict__ y,
                      _Float16* __restrict__ xc, _Float16* __restrict__ yc,
                      float* __restrict__ sq, double* __restrict__ cs) {
    const int mat = blockIdx.y;
    const float* src = mat ? y : x;
    _Float16* dst = mat ? yc : xc;
    const int w = threadIdx.x >> 6, lane = threadIdx.x & 63;
    const int r0 = blockIdx.x * 32 + w * 8;
    __shared__ float lds[4][256];
    float4 colacc = {0.f, 0.f, 0.f, 0.f};
    #pragma unroll
    for (int r = 0; r < 8; ++r) {
        const int row = r0 + r;
        const float4 v = *(const float4*)(src + (size_t)row * D + lane * 4);
        f16x4 h;
        h.x = (_Float16)v.x; h.y = (_Float16)v.y;
        h.z = (_Float16)v.z; h.w = (_Float16)v.w;
        *(f16x4*)(dst + (size_t)row * D + lane * 4) = h;
        float s = v.x * v.x + v.y * v.y + v.z * v.z + v.w * v.w;
        #pragma unroll
        for (int off = 32; off; off >>= 1) s += __shfl_down(s, off);
        if (lane == 0) sq[mat * N + row] = s;
        colacc.x += v.x; colacc.y += v.y; colacc.z += v.z; colacc.w += v.w;
    }
    *(float4*)&lds[w][lane * 4] = colacc;
    __syncthreads();
    const int t = threadIdx.x;   // column
    const float part = lds[0][t] + lds[1][t] + lds[2][t] + lds[3][t];
    atomicAdd(&cs[mat * D + t], (double)part);
}

// ---- K2: stats -> closed-form sum(d2) -> base coefficient c4 per pass ----
// Terms are u^(2^(4-k)) with u = exp2(-d2*c4), c4 = L2E/(16*bw + eps).
__global__ void k_prep(const float* __restrict__ sq, const double* __restrict__ cs,
                       float* __restrict__ coef, double* __restrict__ acc) {
    const int t = threadIdx.x;  // 256
    double sx = 0, sy = 0;
    for (int i = t; i < N; i += 256) { sx += (double)sq[i]; sy += (double)sq[N + i]; }
    const double cx = cs[t], cy = cs[D + t];
    double v[5] = {sx, sy, cx * cx, cy * cy, cx * cy};
    #pragma unroll
    for (int k = 0; k < 5; ++k)
        for (int off = 32; off; off >>= 1) v[k] += __shfl_down(v[k], off);
    __shared__ double red[4][5];
    const int w = t >> 6, lane = t & 63;
    if (lane == 0) for (int k = 0; k < 5; ++k) red[w][k] = v[k];
    __syncthreads();
    if (t == 0) {
        double Sx = 0, Sy = 0, Cxx = 0, Cyy = 0, Cxy = 0;
        for (int q = 0; q < 4; ++q) {
            Sx += red[q][0]; Sy += red[q][1];
            Cxx += red[q][2]; Cyy += red[q][3]; Cxy += red[q][4];
        }
        const double ns = 2.0 * N;
        const double denom = ns * ns - ns;
        const double sd[3] = {
            2.0 * N * Sx - 2.0 * Cxx,
            2.0 * N * Sy - 2.0 * Cyy,
            (double)N * Sx + (double)N * Sy - 2.0 * Cxy };
        const double L2E = 1.4426950408889634;
        for (int q = 0; q < 3; ++q) {
            const double bw = sd[q] / denom / 4.0;
            coef[q] = (float)(L2E / (16.0 * bw + 1e-5));
        }
        acc[0] = 0.0; acc[1] = 0.0; acc[2] = 0.0;
    }
}

// ---- K3: all three Gram passes in one dispatch. fp16 MFMA (K=256), BK=32
// DOUBLE-BUFFERED LDS 2-phase pipeline (stage next || compute cur, one
// vmcnt(0)+barrier per step), full XOR swizzle (lg ^ (fr&3) ^ (fr>>2)) via
// pre-swizzled global source, factored single-exp epilogue. ----
__global__ __launch_bounds__(256) void k_mmd(
    const _Float16* __restrict__ xc, const _Float16* __restrict__ yc,
    const float* __restrict__ sq, const float* __restrict__ coefs,
    double* __restrict__ acc) {
    __shared__ __align__(16) _Float16 As[2 * BT * BK];   // 2 x 8 KB
    __shared__ __align__(16) _Float16 Bs[2 * BT * BK];   // 2 x 8 KB
    __shared__ double red[4];

    // XCD-aware swizzle (TOTAL % 8 == 0)
    const int bid = (blockIdx.x & 7) * (TOTAL / 8) + (blockIdx.x >> 3);

    // pass decode: 0 = xx (tri), 1 = yy (tri), 2 = xy (full)
    int p, b;
    if (bid < TRI)          { p = 0; b = bid; }
    else if (bid < 2 * TRI) { p = 1; b = bid - TRI; }
    else                    { p = 2; b = bid - 2 * TRI; }
    const _Float16* A = (p == 1) ? yc : xc;
    const _Float16* B = (p == 0) ? xc : yc;
    const float* sqA = (p == 1) ? sq + N : sq;
    const float* sqB = (p == 0) ? sq : sq + N;
    const float c4 = coefs[p];

    int bi, bj;
    if (p < 2) {  // upper-triangular decode (bi <= bj)
        int rem = b, r = 0;
        while (rem >= NB2 - r) { rem -= NB2 - r; ++r; }
        bi = r; bj = r + rem;
    } else { bi = b >> 5; bj = b & 31; }

    const int tid = threadIdx.x;
    // --- staging: thread t fills LDS slot t*16 (+q*4096, q=0..1) ---
    // LDS row = q*64 + (t>>2), pos = t&3. LDS[row][pos] holds global chunk
    // pos ^ f(row), f(row) = (row ^ (row>>2)) & 3  (same f for both q).
    const int srow = tid >> 2;
    const int sc = (tid & 3) ^ (srow & 3) ^ ((srow >> 2) & 3);
    const char* gA = (const char*)A + (size_t)(bi * BT + srow) * (D * 2) + sc * 16;
    const char* gB = (const char*)B + (size_t)(bj * BT + srow) * (D * 2) + sc * 16;
    char* lA = (char*)As + tid * 16;
    char* lB = (char*)Bs + tid * 16;

    // --- fragment read addressing ---
    const int lane = tid & 63, w = tid >> 6;
    const int wr = (w >> 1) * 64, wc = (w & 1) * 64;   // wave quadrant
    const int fr = lane & 15;
    const int lg = lane >> 4;                          // k-chunk within MFMA
    // pos = lg ^ f(row); f(row) = (fr&3) ^ (fr>>2) for rows wr+m*16+fr
    const int ch = (lg ^ (fr & 3) ^ (fr >> 2)) * 16;
    const char* rA = (const char*)As + (wr + fr) * 64 + ch;
    const char* rB = (const char*)Bs + (wc + fr) * 64 + ch;

    f32x4 accv[4][4];
    #pragma unroll
    for (int m = 0; m < 4; ++m)
        #pragma unroll
        for (int n = 0; n < 4; ++n) accv[m][n] = {0.f, 0.f, 0.f, 0.f};

    // prologue: stage K-step 0 into buffer 0
    gld_lds16(gA, lA);
    gld_lds16(gA + 64 * (D * 2), lA + 4096);
    gld_lds16(gB, lB);
    gld_lds16(gB + 64 * (D * 2), lB + 4096);
    __syncthreads();                        // vmcnt(0) drain + barrier

    #pragma unroll
    for (int kt = 0; kt < KT; ++kt) {
        const int c = kt & 1;
        if (kt + 1 < KT) {                  // issue next tile's loads first
            const int kb = (kt + 1) * (BK * 2);
            const int co = (c ^ 1) * 8192;
            gld_lds16(gA + kb, lA + co);
            gld_lds16(gA + kb + 64 * (D * 2), lA + co + 4096);
            gld_lds16(gB + kb, lB + co);
            gld_lds16(gB + kb + 64 * (D * 2), lB + co + 4096);
        }
        // compute current buffer
        const int co = c * 8192;
        f16x8 af[4], bf[4];
        #pragma unroll
        for (int m = 0; m < 4; ++m)
            af[m] = *(const f16x8*)(rA + co + m * 1024);
        #pragma unroll
        for (int n = 0; n < 4; ++n)
            bf[n] = *(const f16x8*)(rB + co + n * 1024);
        #pragma unroll
        for (int m = 0; m < 4; ++m)
            #pragma unroll
            for (int n = 0; n < 4; ++n)
                accv[m][n] = __builtin_amdgcn_mfma_f32_16x16x32_f16(
                    af[m], bf[n], accv[m][n], 0, 0, 0);
        if (kt + 1 < KT) __syncthreads();   // next tile landed (vmcnt(0)+barrier)
    }

    // --- epilogue: arg = -d2*c4 (clamped <= 0); u = exp2(arg);
    //     sum over 5 bandwidths = u + u^2 + u^4 + u^8 + u^16 ---
    const float c2x = 2.f * c4;
    const int row0 = bi * BT + wr + lg * 4;            // C/D: row=(l>>4)*4+reg
    const int col0 = bj * BT + wc + fr;                // C/D: col=l&15
    float asa[4][4], bsb[4];
    #pragma unroll
    for (int m = 0; m < 4; ++m) {
        const f32x4 sa = *(const f32x4*)(sqA + row0 + m * 16);
        #pragma unroll
        for (int i = 0; i < 4; ++i) asa[m][i] = sa[i] * c4;
    }
    #pragma unroll
    for (int n = 0; n < 4; ++n) bsb[n] = sqB[col0 + n * 16] * c4;
    float s = 0.f;
    #pragma unroll
    for (int m = 0; m < 4; ++m)
        #pragma unroll
        for (int n = 0; n < 4; ++n)
            #pragma unroll
            for (int i = 0; i < 4; ++i) {
                float arg = fmaf(accv[m][n][i], c2x, -(asa[m][i] + bsb[n]));
                arg = fminf(arg, 0.f);                 // d2 >= 0 clamp
                const float u = __builtin_amdgcn_exp2f(arg);
                const float u2 = u * u, u4 = u2 * u2;
                const float u8 = u4 * u4, u16 = u8 * u8;
                s += (u + u2) + (u4 + u8) + u16;
            }
    if (p < 2 && bi != bj) s *= 2.f;   // triangular symmetry weight

    double sd = (double)s;
    #pragma unroll
    for (int off = 32; off; off >>= 1) sd += __shfl_down(sd, off);
    if (lane == 0) red[w] = sd;
    __syncthreads();
    if (tid == 0) atomicAdd(&acc[p], red[0] + red[1] + red[2] + red[3]);
}

// ---- K4: combine ----
__global__ void k_final(const double* __restrict__ acc, float* __restrict__ out) {
    const double inv = 1.0 / ((double)N * (double)N);
    out[0] = (float)((acc[0] + acc[1] - 2.0 * acc[2]) * inv);
}

extern "C" void kernel_launch(void* const* d_in, const int* in_sizes, int n_in,
                              void* d_out, int out_size, void* d_ws, size_t ws_size,
                              hipStream_t stream) {
    const float* x = (const float*)d_in[0];
    const float* y = (const float*)d_in[1];
    float* out = (float*)d_out;

    double* wsd = (double*)d_ws;
    double* acc = wsd;                        // 3 doubles (zeroed in k_prep)
    double* cs  = wsd + 8;                    // 512 doubles (zeroed by memset)
    float*  sq  = (float*)(wsd + 520);        // 8192 floats
    float*  coef = sq + 2 * N;                // 3 floats
    char* base = (char*)d_ws;
    _Float16* xc = (_Float16*)(base + 40960);                       // 2 MB
    _Float16* yc = (_Float16*)(base + 40960 + (size_t)N * D * 2);   // 2 MB

    hipMemsetAsync(cs, 0, 512 * sizeof(double), stream);
    k_cvt<<<dim3(N / 32, 2), 256, 0, stream>>>(x, y, xc, yc, sq, cs);
    k_prep<<<1, 256, 0, stream>>>(sq, cs, coef, acc);
    k_mmd<<<TOTAL, 256, 0, stream>>>(xc, yc, sq, coef, acc);
    k_final<<<1, 1, 0, stream>>>(acc, out);
}